// Round 3
// baseline (247.693 us; speedup 1.0000x reference)
//
#include <hip/hip_runtime.h>

// RGCN_70566312673746: out[e,o] = xsum[e] * sum_r (1/cs[e,r]) * Wsum[r,o]
//   Wsum[r,o] = sum_i W[r,i,o].  E=100000, R=64, I=256, O=256.
//   edge_index is UNUSED by the reference output.
//
// Round-5 structure (R2 post-mortem: dur_us=243 while BOTH app kernels are
// absent from rocprof top-5 (each <61us) -> the timed region includes the
// per-iteration 409.6MB harness poison fill (~61us) + restore dispatches;
// controllable app slice is only ~60-100us. Also the R4 fused 1024-thread
// pre_kernel coincided with a +11us regression vs R3. App data-motion floor:
// W 16.8 + x 102.4 + cs 25.6 + out 102.4 = 247MB ~= 39us @ 6.3TB/s):
//   K1 wsum_kernel: tiny 16.8MB Wsum^T bf16 pass, verbatim the
//      harness-verified R3 kernel. 256 blocks x 1024. ~5us.
//   K2 out_kernel: xsum FUSED IN. The separate 102.4MB xsum pass, its
//      workspace round-trip, and its dependent launch are deleted. Wave owns
//      one 16-row e-tile (6252 waves, perfect balance); the 4 lanes sharing
//      lm each read 64 contiguous floats of row e0 (16 independent float4s),
//      2x __shfl_xor(16,32) completes the row sum. MFMA mapping (D[o][e],
//      A=W^T bf16 frags re-read from 32KB L2-resident wsumT, B=rcp(cs) bf16)
//      is byte-identical to the harness-verified R3/R4 kernel.

constexpr int En = 100000;
constexpr int Rn = 64;
constexpr int In = 256;
constexpr int On = 256;
constexpr int TILES = En / 16;   // 6250, exact

typedef short bf16x8 __attribute__((ext_vector_type(8)));
typedef float floatx4 __attribute__((ext_vector_type(4)));

// round-to-nearest-even fp32 -> bf16 bits (finite values only)
static __device__ __forceinline__ short f2bf(float f) {
    unsigned u = __builtin_bit_cast(unsigned, f);
    unsigned r = (u + 0x7FFFu + ((u >> 16) & 1u)) >> 16;
    return (short)r;
}

// ---- K1: Wsum^T[o][r] = bf16(sum_i W[r,i,o]).  block b: r=b>>2, o-quarter
//      h=b&3.  1024 threads: o_local = t&63, i-chunk ic = t>>6 (16 i's). ----
__global__ __launch_bounds__(1024) void wsum_kernel(const float* __restrict__ W,
                                                    short* __restrict__ wsumT) {
    __shared__ float red[16][65];
    const int r  = blockIdx.x >> 2;
    const int h  = blockIdx.x & 3;
    const int ol = threadIdx.x & 63;
    const int ic = threadIdx.x >> 6;
    const int o  = h * 64 + ol;
    const float* base = W + ((size_t)r * In + (size_t)ic * 16) * On + o;
    float s = 0.f;
#pragma unroll
    for (int i = 0; i < 16; ++i) s += base[(size_t)i * On];
    red[ic][ol] = s;
    __syncthreads();
    if (ic == 0) {
        float t = 0.f;
#pragma unroll
        for (int j = 0; j < 16; ++j) t += red[j][ol];
        wsumT[o * Rn + r] = f2bf(t);
    }
}

// ---- K2: out rows, xsum fused.  ONE 16-e-row tile per wave, straight-line.
//      Lane (q = ln>>4, lm = ln&15): e0 = gw*16+lm; lane covers x columns
//      [q*64, q*64+64).  MFMA computes D[o][e] (A = W^T frags, B = recip):
//        o = ot*16 + q*4 + rg, e = gw*16 + lm -> float4 stores. ----
__global__ __launch_bounds__(256, 4) void out_kernel(const float* __restrict__ x,
                                                     const float* __restrict__ cs,
                                                     const short* __restrict__ wsumT,
                                                     float* __restrict__ out) {
    const int gw = (blockIdx.x * 256 + (int)threadIdx.x) >> 6;
    if (gw >= TILES) return;            // no barriers below: early-exit safe
    const int ln = threadIdx.x & 63;
    const int lm = ln & 15;
    const int q  = ln >> 4;
    const int e0 = gw * 16 + lm;

    // ---- fused xsum: sum of x[e0, q*64 .. q*64+63], 16 independent float4s
    const floatx4* xp = (const floatx4*)(x + (size_t)e0 * In + q * 64);
    floatx4 a0 = {0.f, 0.f, 0.f, 0.f}, a1 = a0, a2 = a0, a3 = a0;
#pragma unroll
    for (int j = 0; j < 4; ++j) {
        a0 += xp[4 * j + 0];
        a1 += xp[4 * j + 1];
        a2 += xp[4 * j + 2];
        a3 += xp[4 * j + 3];
    }
    const floatx4 at = (a0 + a1) + (a2 + a3);
    float s = (at[0] + at[1]) + (at[2] + at[3]);
    // lanes {lm, lm+16, lm+32, lm+48} hold the 4 quarters of row e0
    s += __shfl_xor(s, 16, 64);
    s += __shfl_xor(s, 32, 64);
    const float xs = s;

    // ---- cs fragments -> B frags: B[k=r=q*8+j][n=e_local=lm] = bf16(1/cs)
    const float* p = cs + (size_t)e0 * Rn + q * 8;
    const float4 d0 = *(const float4*)p;
    const float4 d1 = *(const float4*)(p + 4);
    const float4 d2 = *(const float4*)(p + 32);
    const float4 d3 = *(const float4*)(p + 36);
    bf16x8 b0, b1;
    {
        const float rv[16] = {d0.x, d0.y, d0.z, d0.w, d1.x, d1.y, d1.z, d1.w,
                              d2.x, d2.y, d2.z, d2.w, d3.x, d3.y, d3.z, d3.w};
#pragma unroll
        for (int j = 0; j < 8; ++j) {
            b0[j] = f2bf(__builtin_amdgcn_rcpf(rv[j]));
            b1[j] = f2bf(__builtin_amdgcn_rcpf(rv[8 + j]));
        }
    }

    float* orow = out + (size_t)e0 * On + q * 4;
    const short* wb = wsumT + lm * Rn + q * 8;   // A[m=o_local=lm][k=r=q*8+j]
#pragma unroll
    for (int ot = 0; ot < 16; ++ot) {
        const short* wp = wb + ot * 16 * Rn;
        const bf16x8 wa0 = *(const bf16x8*)wp;          // r = q*8 .. q*8+7
        const bf16x8 wa1 = *(const bf16x8*)(wp + 32);   // r = 32+q*8 ..
        floatx4 acc = {0.f, 0.f, 0.f, 0.f};
        acc = __builtin_amdgcn_mfma_f32_16x16x32_bf16(wa0, b0, acc, 0, 0, 0);
        acc = __builtin_amdgcn_mfma_f32_16x16x32_bf16(wa1, b1, acc, 0, 0, 0);
        // D: row=q*4+rg -> o, col=lm -> e; 4 consecutive o => float4 store
        const float4 st = make_float4(acc[0] * xs, acc[1] * xs,
                                      acc[2] * xs, acc[3] * xs);
        *(float4*)(orow + ot * 16) = st;
    }
}

extern "C" void kernel_launch(void* const* d_in, const int* in_sizes, int n_in,
                              void* d_out, int out_size, void* d_ws, size_t ws_size,
                              hipStream_t stream) {
    const float* x  = (const float*)d_in[0];   // (E, I) fp32
    const float* cs = (const float*)d_in[1];   // (E, R) fp32
    const float* W  = (const float*)d_in[2];   // (R, I, O) fp32
    // d_in[3] = edge_index: unused by the reference output.
    float* out = (float*)d_out;

    short* wsumT = (short*)d_ws;               // 32 KB bf16 [o][r]

    wsum_kernel<<<dim3(256), dim3(1024), 0, stream>>>(W, wsumT);
    out_kernel<<<dim3((TILES * 64 + 255) / 256), dim3(256), 0, stream>>>(
        x, cs, wsumT, out);
}

// Round 5
// 238.757 us; speedup vs baseline: 1.0374x; 1.0374x over previous
//
#include <hip/hip_runtime.h>

// RGCN_70566312673746: out[e,o] = xsum[e] * sum_r (1/cs[e,r]) * Wsum[r,o]
//   Wsum[r,o] = sum_i W[r,i,o].  E=100000, R=64, I=256, O=256.
//   edge_index is UNUSED by the reference output.
//
// Round-6 structure (R3 post-mortem: out_kernel finally visible in rocprof —
// 91us @ 2.17TB/s (27% peak), MfmaUtil 1.3%, VALUBusy 2.5%, VGPR 36 ->
// LATENCY-bound. Cause: the MFMA lane mapping (e=lm) made every x/cs global
// load per-lane ROW-STRIDED: one float4 instr touched 64 distinct 64B lines
// (16 rows x 4 quarters) instead of 16 contiguous ones, and VGPR=36 kept only
// ~4 loads in flight. Also dur_us(247) - app(96us) => ~150us fixed harness
// reset cost in the timed region; controllable floor ~39us @ 6.3TB/s):
//   K1 wsum_kernel: verbatim harness-verified Wsum^T bf16 pass (~5us).
//   K2 out_kernel: all global reads now WAVE-CONTIGUOUS.
//      - x: 16 rows read as 16 x 1KB coalesced instrs (instr j = row j),
//        8 in flight; row sum via 6-level shfl_xor butterfly; xs = s[lm]
//        via unrolled uniform-select (compile-time indices only).
//      - cs: 16x64f tile read as 4 x 1KB coalesced instrs -> per-wave LDS
//        scratch (stride 68 floats; same-wave ds_write->ds_read, NO barrier)
//        -> re-read as the identical d0..d3 frag quartet of the verified
//        kernel (numerics unchanged: rcp+f2bf at frag build).
//      - MFMA mapping (D[o][e], A=W^T from 32KB hot wsumT, B=rcp(cs)) and
//        the float4 stores are byte-identical to the verified R3 kernel.
//      __launch_bounds__(256,4): 128-VGPR budget for deep load ILP.
//
// (Round-4 resubmission: bench died on GPUAcquisitionTimeout — no signal;
// kernel unchanged.)

constexpr int En = 100000;
constexpr int Rn = 64;
constexpr int In = 256;
constexpr int On = 256;
constexpr int TILES = En / 16;   // 6250, exact
constexpr int CSP   = 68;        // padded cs row stride in LDS (floats)

typedef short bf16x8 __attribute__((ext_vector_type(8)));
typedef float floatx4 __attribute__((ext_vector_type(4)));

// round-to-nearest-even fp32 -> bf16 bits (finite values only)
static __device__ __forceinline__ short f2bf(float f) {
    unsigned u = __builtin_bit_cast(unsigned, f);
    unsigned r = (u + 0x7FFFu + ((u >> 16) & 1u)) >> 16;
    return (short)r;
}

// ---- K1: Wsum^T[o][r] = bf16(sum_i W[r,i,o]).  block b: r=b>>2, o-quarter
//      h=b&3.  1024 threads: o_local = t&63, i-chunk ic = t>>6 (16 i's). ----
__global__ __launch_bounds__(1024) void wsum_kernel(const float* __restrict__ W,
                                                    short* __restrict__ wsumT) {
    __shared__ float red[16][65];
    const int r  = blockIdx.x >> 2;
    const int h  = blockIdx.x & 3;
    const int ol = threadIdx.x & 63;
    const int ic = threadIdx.x >> 6;
    const int o  = h * 64 + ol;
    const float* base = W + ((size_t)r * In + (size_t)ic * 16) * On + o;
    float s = 0.f;
#pragma unroll
    for (int i = 0; i < 16; ++i) s += base[(size_t)i * On];
    red[ic][ol] = s;
    __syncthreads();
    if (ic == 0) {
        float t = 0.f;
#pragma unroll
        for (int j = 0; j < 16; ++j) t += red[j][ol];
        wsumT[o * Rn + r] = f2bf(t);
    }
}

// ---- K2: one 16-e-row tile per wave (6252 waves), straight-line, no
//      barriers.  Lane (q = ln>>4, lm = ln&15): e0 = gw*16+lm.
//      MFMA computes D[o][e]: o = ot*16 + q*4 + rg, e = gw*16 + lm. ----
__global__ __launch_bounds__(256, 4) void out_kernel(const float* __restrict__ x,
                                                     const float* __restrict__ cs,
                                                     const short* __restrict__ wsumT,
                                                     float* __restrict__ out) {
    __shared__ float lds_cs[4][16 * CSP];      // per-wave scratch, no sharing
    const int wid = (int)threadIdx.x >> 6;
    const int gw  = (int)blockIdx.x * 4 + wid;
    if (gw >= TILES) return;                   // no barriers: early-exit safe
    const int ln = (int)threadIdx.x & 63;
    const int lm = ln & 15;
    const int q  = ln >> 4;

    // ---- cs tile: 16 rows x 256B = 4KB as 4 coalesced 1KB loads.
    //      Instr k: lane ln holds row 4k+(ln>>4), floats (ln&15)*4 .. +4.
    const float4* csb = (const float4*)(cs + (size_t)gw * 16 * Rn);
    const float4 cv0 = csb[0 * 64 + ln];
    const float4 cv1 = csb[1 * 64 + ln];
    const float4 cv2 = csb[2 * 64 + ln];
    const float4 cv3 = csb[3 * 64 + ln];

    // ---- x tile: 16 rows x 1KB as 16 coalesced loads (instr j = row j),
    //      8 in flight; full-wave butterfly reduce per row.
    const float4* xb = (const float4*)(x + (size_t)gw * 16 * In);
    float s[16];
#pragma unroll
    for (int j0 = 0; j0 < 16; j0 += 8) {
        float4 v[8];
#pragma unroll
        for (int j = 0; j < 8; ++j) v[j] = xb[(j0 + j) * 64 + ln];
#pragma unroll
        for (int j = 0; j < 8; ++j) {
            float t = (v[j].x + v[j].y) + (v[j].z + v[j].w);
#pragma unroll
            for (int m = 1; m <= 32; m <<= 1) t += __shfl_xor(t, m, 64);
            s[j0 + j] = t;   // wave-uniform: sum of row j0+j
        }
    }
    float xs = s[0];
#pragma unroll
    for (int j = 1; j < 16; ++j) xs = (lm == j) ? s[j] : xs;  // xs = s[lm]

    // ---- cs -> per-wave LDS (stride 68 breaks bank alignment), then read
    //      back the exact d0..d3 quartet the verified frag-build consumed.
    {
        float* lw = &lds_cs[wid][(ln >> 4) * CSP + (ln & 15) * 4];
        *(float4*)(lw + 0 * 4 * CSP) = cv0;
        *(float4*)(lw + 1 * 4 * CSP) = cv1;
        *(float4*)(lw + 2 * 4 * CSP) = cv2;
        *(float4*)(lw + 3 * 4 * CSP) = cv3;
    }
    const float* lr = &lds_cs[wid][lm * CSP + q * 8];
    const float4 d0 = *(const float4*)(lr + 0);    // r = q*8   .. q*8+3
    const float4 d1 = *(const float4*)(lr + 4);    // r = q*8+4 .. q*8+7
    const float4 d2 = *(const float4*)(lr + 32);   // r = 32+q*8 ..
    const float4 d3 = *(const float4*)(lr + 36);

    // ---- B frags: B[k=r=q*8+j][n=e_local=lm] = bf16(1/cs[e][r])
    bf16x8 b0, b1;
    {
        const float rv[16] = {d0.x, d0.y, d0.z, d0.w, d1.x, d1.y, d1.z, d1.w,
                              d2.x, d2.y, d2.z, d2.w, d3.x, d3.y, d3.z, d3.w};
#pragma unroll
        for (int j = 0; j < 8; ++j) {
            b0[j] = f2bf(__builtin_amdgcn_rcpf(rv[j]));
            b1[j] = f2bf(__builtin_amdgcn_rcpf(rv[8 + j]));
        }
    }

    float* orow = out + (size_t)(gw * 16 + lm) * On + q * 4;
    const short* wb = wsumT + lm * Rn + q * 8;   // A[m=o_local=lm][k=r=q*8+j]
#pragma unroll
    for (int ot = 0; ot < 16; ++ot) {
        const short* wp = wb + ot * 16 * Rn;
        const bf16x8 wa0 = *(const bf16x8*)wp;          // r = q*8 .. q*8+7
        const bf16x8 wa1 = *(const bf16x8*)(wp + 32);   // r = 32+q*8 ..
        floatx4 acc = {0.f, 0.f, 0.f, 0.f};
        acc = __builtin_amdgcn_mfma_f32_16x16x32_bf16(wa0, b0, acc, 0, 0, 0);
        acc = __builtin_amdgcn_mfma_f32_16x16x32_bf16(wa1, b1, acc, 0, 0, 0);
        // D: row=q*4+rg -> o, col=lm -> e; 4 consecutive o => float4 store
        const float4 st = make_float4(acc[0] * xs, acc[1] * xs,
                                      acc[2] * xs, acc[3] * xs);
        *(float4*)(orow + ot * 16) = st;
    }
}

extern "C" void kernel_launch(void* const* d_in, const int* in_sizes, int n_in,
                              void* d_out, int out_size, void* d_ws, size_t ws_size,
                              hipStream_t stream) {
    const float* x  = (const float*)d_in[0];   // (E, I) fp32
    const float* cs = (const float*)d_in[1];   // (E, R) fp32
    const float* W  = (const float*)d_in[2];   // (R, I, O) fp32
    // d_in[3] = edge_index: unused by the reference output.
    float* out = (float*)d_out;

    short* wsumT = (short*)d_ws;               // 32 KB bf16 [o][r]

    wsum_kernel<<<dim3(256), dim3(1024), 0, stream>>>(W, wsumT);
    out_kernel<<<dim3((TILES + 3) / 4), dim3(256), 0, stream>>>(
        x, cs, wsumT, out);
}

// Round 6
// 235.729 us; speedup vs baseline: 1.0508x; 1.0128x over previous
//
#include <hip/hip_runtime.h>

// RGCN_70566312673746: out[e,o] = xsum[e] * sum_r (1/cs[e,r]) * Wsum[r,o]
//   Wsum[r,o] = sum_i W[r,i,o].  E=100000, R=64, I=256, O=256.
//   edge_index is UNUSED by the reference output.
//
// Round-7 structure (R4 post-mortem: coalescing x/cs changed FETCH 89->62.7MB
// and VALUBusy 2.5->4.3% but duration stayed EXACTLY 91us -> x/cs loads were
// never the critical path. Invariants across R3/R4: VGPR=36 and the per-tile
// wsumT re-reads: 32 scattered loads/wave consumed immediately by MFMA; at 36
// VGPR the compiler cannot prefetch -> a fully serialized ~32 x L2-latency
// chain (~16k cyc) + pairwise-serialized x loads ~= the measured ~36k
// cyc/wave. The pre-session R0 kernel with the 128-VGPR W-frag hoist ran
// <62us despite scattered cs -> the hoist (32 INDEPENDENT loads, one latency,
// structurally forcing a big VGPR allocation) is the fix, amortized over
// multiple tiles):
//   K1 wsum_kernel: verbatim harness-verified Wsum^T bf16 pass (~5us).
//   K2 out_kernel: R0's hoist+multi-tile skeleton x R4's coalesced paths.
//      - W^T frags hoisted ONCE per wave into 128 VGPRs (32 independent
//        loads, all in flight); no wsumT traffic inside the tile loop.
//      - 2048 waves (512 blocks), grid-stride over 6250 tiles (~3/wave);
//        __launch_bounds__(256,2): ~230 VGPR OK, 8 waves/CU.
//      - x: 16 coalesced 1KB row loads, 8 in flight; 6-level shfl_xor
//        butterfly row sums; xs = s[lm] by unrolled uniform-select. (R4)
//      - cs: 4 coalesced 1KB loads -> per-wave padded LDS scratch (no
//        barrier, same-wave DS ordering) -> verified d0..d3 frag quartet. (R4)
//      - MFMA mapping (D[o][e]: o=ot*16+q*4+rg, e=t*16+lm) and float4
//        stores byte-identical to the harness-verified R3/R4 kernels.

constexpr int En = 100000;
constexpr int Rn = 64;
constexpr int In = 256;
constexpr int On = 256;
constexpr int TILES  = En / 16;   // 6250, exact
constexpr int CSP    = 68;        // padded cs row stride in LDS (floats)
constexpr int NWAVES = 2048;      // 512 blocks x 4 waves

typedef short bf16x8 __attribute__((ext_vector_type(8)));
typedef float floatx4 __attribute__((ext_vector_type(4)));

// round-to-nearest-even fp32 -> bf16 bits (finite values only)
static __device__ __forceinline__ short f2bf(float f) {
    unsigned u = __builtin_bit_cast(unsigned, f);
    unsigned r = (u + 0x7FFFu + ((u >> 16) & 1u)) >> 16;
    return (short)r;
}

// ---- K1: Wsum^T[o][r] = bf16(sum_i W[r,i,o]).  block b: r=b>>2, o-quarter
//      h=b&3.  1024 threads: o_local = t&63, i-chunk ic = t>>6 (16 i's). ----
__global__ __launch_bounds__(1024) void wsum_kernel(const float* __restrict__ W,
                                                    short* __restrict__ wsumT) {
    __shared__ float red[16][65];
    const int r  = blockIdx.x >> 2;
    const int h  = blockIdx.x & 3;
    const int ol = threadIdx.x & 63;
    const int ic = threadIdx.x >> 6;
    const int o  = h * 64 + ol;
    const float* base = W + ((size_t)r * In + (size_t)ic * 16) * On + o;
    float s = 0.f;
#pragma unroll
    for (int i = 0; i < 16; ++i) s += base[(size_t)i * On];
    red[ic][ol] = s;
    __syncthreads();
    if (ic == 0) {
        float t = 0.f;
#pragma unroll
        for (int j = 0; j < 16; ++j) t += red[j][ol];
        wsumT[o * Rn + r] = f2bf(t);
    }
}

// ---- K2: W-frag hoist + grid-stride tiles.  Lane (q = ln>>4, lm = ln&15):
//      e = t*16+lm.  MFMA computes D[o][e]: o = ot*16 + q*4 + rg. ----
__global__ __launch_bounds__(256, 2) void out_kernel(const float* __restrict__ x,
                                                     const float* __restrict__ cs,
                                                     const short* __restrict__ wsumT,
                                                     float* __restrict__ out) {
    __shared__ float lds_cs[4][16 * CSP];      // per-wave scratch, no sharing
    const int wid = (int)threadIdx.x >> 6;
    const int gw  = (int)blockIdx.x * 4 + wid; // 0..2047, all < TILES
    const int ln  = (int)threadIdx.x & 63;
    const int lm  = ln & 15;
    const int q   = ln >> 4;

    // ---- hoist W^T fragments for all 16 o-tiles: 32 INDEPENDENT loads,
    //      dest = the hoist array itself -> all issue back-to-back, one
    //      latency total.  A[m=o_local=lm][k=r=q*8+j].
    bf16x8 wa0[16], wa1[16];
    const short* wbase = wsumT + lm * Rn + q * 8;
#pragma unroll
    for (int ot = 0; ot < 16; ++ot) {
        const short* p = wbase + ot * 16 * Rn;
        wa0[ot] = *(const bf16x8*)p;          // r = q*8 .. q*8+7
        wa1[ot] = *(const bf16x8*)(p + 32);   // r = 32+q*8 ..
    }

    for (int t = gw; t < TILES; t += NWAVES) {
        // ---- cs tile: 16 rows x 256B = 4KB as 4 coalesced 1KB loads.
        const float4* csb = (const float4*)(cs + (size_t)t * 16 * Rn);
        const float4 cv0 = csb[0 * 64 + ln];
        const float4 cv1 = csb[1 * 64 + ln];
        const float4 cv2 = csb[2 * 64 + ln];
        const float4 cv3 = csb[3 * 64 + ln];

        // ---- x tile: 16 rows x 1KB as 16 coalesced loads, 8 in flight;
        //      full-wave butterfly reduce per row.
        const float4* xb = (const float4*)(x + (size_t)t * 16 * In);
        float s[16];
#pragma unroll
        for (int j0 = 0; j0 < 16; j0 += 8) {
            float4 v[8];
#pragma unroll
            for (int j = 0; j < 8; ++j) v[j] = xb[(j0 + j) * 64 + ln];
#pragma unroll
            for (int j = 0; j < 8; ++j) {
                float tt = (v[j].x + v[j].y) + (v[j].z + v[j].w);
#pragma unroll
                for (int m = 1; m <= 32; m <<= 1) tt += __shfl_xor(tt, m, 64);
                s[j0 + j] = tt;   // wave-uniform: sum of row j0+j
            }
        }
        float xs = s[0];
#pragma unroll
        for (int j = 1; j < 16; ++j) xs = (lm == j) ? s[j] : xs;  // xs = s[lm]

        // ---- cs -> per-wave LDS (stride 68 breaks bank alignment), then
        //      read back the exact d0..d3 quartet (same-wave DS ordering,
        //      no barrier; DS ops of one wave execute in order).
        {
            float* lw = &lds_cs[wid][(ln >> 4) * CSP + (ln & 15) * 4];
            *(float4*)(lw + 0 * 4 * CSP) = cv0;
            *(float4*)(lw + 1 * 4 * CSP) = cv1;
            *(float4*)(lw + 2 * 4 * CSP) = cv2;
            *(float4*)(lw + 3 * 4 * CSP) = cv3;
        }
        const float* lr = &lds_cs[wid][lm * CSP + q * 8];
        const float4 d0 = *(const float4*)(lr + 0);    // r = q*8   .. q*8+3
        const float4 d1 = *(const float4*)(lr + 4);    // r = q*8+4 .. q*8+7
        const float4 d2 = *(const float4*)(lr + 32);   // r = 32+q*8 ..
        const float4 d3 = *(const float4*)(lr + 36);

        // ---- B frags: B[k=r=q*8+j][n=e_local=lm] = bf16(1/cs[e][r])
        bf16x8 b0, b1;
        {
            const float rv[16] = {d0.x, d0.y, d0.z, d0.w, d1.x, d1.y, d1.z, d1.w,
                                  d2.x, d2.y, d2.z, d2.w, d3.x, d3.y, d3.z, d3.w};
#pragma unroll
            for (int j = 0; j < 8; ++j) {
                b0[j] = f2bf(__builtin_amdgcn_rcpf(rv[j]));
                b1[j] = f2bf(__builtin_amdgcn_rcpf(rv[8 + j]));
            }
        }

        float* orow = out + (size_t)(t * 16 + lm) * On + q * 4;
#pragma unroll
        for (int ot = 0; ot < 16; ++ot) {
            floatx4 acc = {0.f, 0.f, 0.f, 0.f};
            acc = __builtin_amdgcn_mfma_f32_16x16x32_bf16(wa0[ot], b0, acc, 0, 0, 0);
            acc = __builtin_amdgcn_mfma_f32_16x16x32_bf16(wa1[ot], b1, acc, 0, 0, 0);
            // D: row=q*4+rg -> o, col=lm -> e; 4 consecutive o => float4 store
            const float4 st = make_float4(acc[0] * xs, acc[1] * xs,
                                          acc[2] * xs, acc[3] * xs);
            *(float4*)(orow + ot * 16) = st;
        }
    }
}

extern "C" void kernel_launch(void* const* d_in, const int* in_sizes, int n_in,
                              void* d_out, int out_size, void* d_ws, size_t ws_size,
                              hipStream_t stream) {
    const float* x  = (const float*)d_in[0];   // (E, I) fp32
    const float* cs = (const float*)d_in[1];   // (E, R) fp32
    const float* W  = (const float*)d_in[2];   // (R, I, O) fp32
    // d_in[3] = edge_index: unused by the reference output.
    float* out = (float*)d_out;

    short* wsumT = (short*)d_ws;               // 32 KB bf16 [o][r]

    wsum_kernel<<<dim3(256), dim3(1024), 0, stream>>>(W, wsumT);
    out_kernel<<<dim3(NWAVES / 4), dim3(256), 0, stream>>>(
        x, cs, wsumT, out);
}